// Round 9
// baseline (412.322 us; speedup 1.0000x reference)
//
#include <hip/hip_runtime.h>
#include <cstdint>
#include <cmath>

typedef unsigned short u16;
typedef __bf16 bf16x8 __attribute__((ext_vector_type(8)));
typedef float  f32x4  __attribute__((ext_vector_type(4)));
typedef unsigned short u16x8 __attribute__((ext_vector_type(8)));

__device__ __forceinline__ u16 f2bf(float f) {
  unsigned u = __float_as_uint(f);
  u += 0x7fffu + ((u >> 16) & 1u);
  return (u16)(u >> 16);
}

#define NEG_BIG (-1.0e30f)

// ---------------------------------------------------------------------------
// Transpose + cast fp32 -> bf16: in [R][C] fp32 -> out [C][R] bf16.
// block (64,4), grid (C/64, R/64)   [proven]
// ---------------------------------------------------------------------------
__global__ __launch_bounds__(256) void transpose_f2b(
    const float* __restrict__ in, u16* __restrict__ out, int R, int C) {
  __shared__ u16 t[64][65];
  const int c0 = blockIdx.x << 6, r0 = blockIdx.y << 6;
  const int x = threadIdx.x, y0 = threadIdx.y;
#pragma unroll
  for (int yy = 0; yy < 64; yy += 4)
    t[yy + y0][x] = f2bf(in[(size_t)(r0 + yy + y0) * C + c0 + x]);
  __syncthreads();
#pragma unroll
  for (int yy = 0; yy < 64; yy += 4)
    out[(size_t)(c0 + yy + y0) * R + r0 + x] = t[x][yy + y0];
}

// ---------------------------------------------------------------------------
// C[M,N] = A[M,K] @ Bt[N,K]^T + bias(fp32). Bt bf16, fp32 accum.
// Plain LDS staging (proven; NO global_load_lds). [byte-frozen from round 7/8]
// ---------------------------------------------------------------------------
template <int MODE, int ADAPT_A>
__global__ __launch_bounds__(256, 2) void gemm_bt(
    const u16* __restrict__ A16, const float* __restrict__ AF,
    const u16* __restrict__ Bt, const float* __restrict__ biasF,
    float* __restrict__ out, u16* __restrict__ qb, u16* __restrict__ kb,
    u16* __restrict__ vt, int N, int K) {
  __shared__ u16 As[4096];
  __shared__ u16 Bs[4096];
  const int tid = threadIdx.x;
  const int lane = tid & 63;
  const int wave = tid >> 6;
  const int ln = lane & 15, quad = lane >> 4;
  const int wm = (wave >> 1) << 6, wn = (wave & 1) << 6;
  const int m0 = blockIdx.y << 7, n0 = blockIdx.x << 7;
  const int srow = tid >> 2, scol = (tid & 3) << 3;

  f32x4 acc[4][4] = {};

  for (int k0 = 0; k0 < K; k0 += 32) {
#pragma unroll
    for (int half = 0; half < 2; ++half) {
      const int arow = m0 + half * 64 + srow;
      u16* dstA = &As[half * 2048 + srow * 32 + scol];
      if (!ADAPT_A) {
        *(u16x8*)dstA = *(const u16x8*)(A16 + (size_t)arow * K + k0 + scol);
      } else {
        const float* p = AF + (size_t)arow * K + k0 + scol;
        u16x8 hv;
#pragma unroll
        for (int j = 0; j < 8; ++j) hv[j] = f2bf(p[j]);
        *(u16x8*)dstA = hv;
      }
      const int brow = n0 + half * 64 + srow;
      *(u16x8*)&Bs[half * 2048 + srow * 32 + scol] =
          *(const u16x8*)(Bt + (size_t)brow * K + k0 + scol);
    }
    __syncthreads();
    bf16x8 af[4], bfr[4];
#pragma unroll
    for (int t = 0; t < 4; ++t) {
      af[t] = *(const bf16x8*)&As[(wm + t * 16 + ln) * 32 + quad * 8];
      bfr[t] = *(const bf16x8*)&Bs[(wn + t * 16 + ln) * 32 + quad * 8];
    }
#pragma unroll
    for (int mt = 0; mt < 4; ++mt)
#pragma unroll
      for (int nt = 0; nt < 4; ++nt)
        acc[mt][nt] = __builtin_amdgcn_mfma_f32_16x16x32_bf16(
            af[mt], bfr[nt], acc[mt][nt], 0, 0, 0);
    __syncthreads();
  }

#pragma unroll
  for (int mt = 0; mt < 4; ++mt) {
#pragma unroll
    for (int nt = 0; nt < 4; ++nt) {
      const int col = n0 + wn + nt * 16 + ln;
      const float bv = biasF[col];
      const int rbase = m0 + wm + mt * 16 + quad * 4;
      if (MODE == 0) {
#pragma unroll
        for (int r = 0; r < 4; ++r)
          out[(size_t)(rbase + r) * N + col] = acc[mt][nt][r] + bv;
      } else {
        const int c = col & 1023;
        const int which = col >> 10;
        const int h = c >> 6, d = c & 63;
        if (which == 0) {
#pragma unroll
          for (int r = 0; r < 4; ++r)
            qb[((size_t)h * 2048 + rbase + r) * 64 + d] =
                f2bf(acc[mt][nt][r] + bv);
        } else if (which == 1) {
#pragma unroll
          for (int r = 0; r < 4; ++r)
            kb[((size_t)h * 2048 + rbase + r) * 64 + d] =
                f2bf(acc[mt][nt][r] + bv);
        } else {
          ushort4 pk;
          pk.x = f2bf(acc[mt][nt][0] + bv);
          pk.y = f2bf(acc[mt][nt][1] + bv);
          pk.z = f2bf(acc[mt][nt][2] + bv);
          pk.w = f2bf(acc[mt][nt][3] + bv);
          *(ushort4*)&vt[((size_t)h * 64 + d) * 2048 + rbase] = pk;
        }
      }
    }
  }
}

// ---------------------------------------------------------------------------
// Causal flash attention v5: no-max softmax (proven r8) + K prefetch pipeline
// + multi-batch in one launch.
// 1 wave = 16 q-rows of one (b,h); 64-key chunks; masked tiles skipped.
// blockIdx = qtu * (nbh/2) + (bh>>1); wave selects bh low bit -> blockIdx&7
// keeps a stable head-pair per XCD slot (L2 locality).
// Next chunk's K fragments are loaded BEFORE the lgkmcnt fence so their
// latency overlaps the P round-trip + PV MFMA.
// Q,K: [nbh][2048][64]; V^T: [nbh][64][2048]; Y: [nbh/16][2048][1024] bf16.
// ---------------------------------------------------------------------------
__global__ __launch_bounds__(128, 4) void attn_fwd(const u16* __restrict__ Qb,
                                                   const u16* __restrict__ Kb,
                                                   const u16* __restrict__ Vt,
                                                   u16* __restrict__ Y,
                                                   int lg_nbh) {
  __shared__ u16 P[2][1152];  // [wave][16 rows * 72]
  const int wave = threadIdx.x >> 6, lane = threadIdx.x & 63;
  const int ln = lane & 15, quad = lane >> 4;
  const int qtu = blockIdx.x >> (lg_nbh - 1);             // 0..127
  const int bh = ((blockIdx.x & ((1 << (lg_nbh - 1)) - 1)) << 1) + wave;
  const int qt = (qtu < 64) ? (127 - qtu) : (qtu - 64);   // heavy tasks first
  const int q0 = qt << 4;         // 16-row q-tile
  const int nch = (qt >> 2) + 1;  // 64-key chunks
  const u16* Qp = Qb + (size_t)bh * (2048 * 64);
  const u16* Kp = Kb + (size_t)bh * (2048 * 64);
  const u16* Vp = Vt + (size_t)bh * (64 * 2048);
  u16* Pw = P[wave];

  bf16x8 qf[2];
#pragma unroll
  for (int kk = 0; kk < 2; ++kk)
    qf[kk] = *(const bf16x8*)&Qp[(q0 + ln) * 64 + kk * 32 + quad * 8];

  f32x4 o[4] = {};
  f32x4 l_run = {};

  const float cs = 0.18033688011112042f;  // log2(e) / sqrt(64)

  // prologue: K fragments for chunk 0
  int ant_cur = (nch == 1) ? ((qt & 3) + 1) : 4;
  bf16x8 kf[4][2];
#pragma unroll
  for (int nt = 0; nt < 4; ++nt)
    if (nt < ant_cur)
#pragma unroll
      for (int kk = 0; kk < 2; ++kk)
        kf[nt][kk] =
            *(const bf16x8*)&Kp[(nt * 16 + ln) * 64 + kk * 32 + quad * 8];

  for (int kc = 0; kc < nch; ++kc) {
    const int k0 = kc << 6;
    const int last = (kc == nch - 1);
    const int ant = ant_cur;         // active 16-key tiles
    const int aks = (ant + 1) >> 1;  // active 32-key PV slices

    bf16x8 vf[4][2];
#pragma unroll
    for (int ks = 0; ks < 2; ++ks)
      if (ks < aks)
#pragma unroll
        for (int dt = 0; dt < 4; ++dt)
          vf[dt][ks] = *(const bf16x8*)&Vp[(dt * 16 + ln) * 2048 + k0 +
                                           ks * 32 + quad * 8];

    f32x4 t[4] = {};  // zero-init: inactive tiles contribute p=0
#pragma unroll
    for (int nt = 0; nt < 4; ++nt)
      if (nt < ant) {
        f32x4 s = {};
        s = __builtin_amdgcn_mfma_f32_16x16x32_bf16(qf[0], kf[nt][0], s, 0, 0,
                                                    0);
        s = __builtin_amdgcn_mfma_f32_16x16x32_bf16(qf[1], kf[nt][1], s, 0, 0,
                                                    0);
        t[nt] = s * cs;
#pragma unroll
        for (int r = 0; r < 4; ++r) {
          if (last && (k0 + nt * 16 + ln > q0 + quad * 4 + r))
            t[nt][r] = NEG_BIG;                         // exp2 -> 0
          t[nt][r] = __builtin_amdgcn_exp2f(t[nt][r]);  // p in (0, ~2^14)
        }
        l_run += t[nt];  // order-free row-sum partial
      }

    // P (C-layout) -> LDS row-major [16 q][64 k], stride 72.
#pragma unroll
    for (int nt = 0; nt < 4; ++nt)
      if (nt < aks * 2)
#pragma unroll
        for (int r = 0; r < 4; ++r)
          Pw[(quad * 4 + r) * 72 + nt * 16 + ln] = f2bf(t[nt][r]);

    // prefetch next chunk's K BEFORE the fence (overlaps LDS trip + PV)
    int ant_next = 4;
    bf16x8 kfn[4][2];
    if (kc + 1 < nch) {
      ant_next = (kc + 1 == nch - 1) ? ((qt & 3) + 1) : 4;
      const int k0n = k0 + 64;
#pragma unroll
      for (int nt = 0; nt < 4; ++nt)
        if (nt < ant_next)
#pragma unroll
          for (int kk = 0; kk < 2; ++kk)
            kfn[nt][kk] = *(const bf16x8*)&Kp[(k0n + nt * 16 + ln) * 64 +
                                              kk * 32 + quad * 8];
    }

    asm volatile("s_waitcnt lgkmcnt(0)" ::: "memory");  // own P writes done
    bf16x8 pa[2];
#pragma unroll
    for (int ks = 0; ks < 2; ++ks)
      if (ks < aks)
        pa[ks] = *(const bf16x8*)&Pw[ln * 72 + ks * 32 + quad * 8];
#pragma unroll
    for (int dt = 0; dt < 4; ++dt)
#pragma unroll
      for (int ks = 0; ks < 2; ++ks)
        if (ks < aks)
          o[dt] = __builtin_amdgcn_mfma_f32_16x16x32_bf16(pa[ks], vf[dt][ks],
                                                          o[dt], 0, 0, 0);

    if (kc + 1 < nch) {
#pragma unroll
      for (int nt = 0; nt < 4; ++nt)
        if (nt < ant_next)
#pragma unroll
          for (int kk = 0; kk < 2; ++kk) kf[nt][kk] = kfn[nt][kk];
    }
    ant_cur = ant_next;
  }

  // one cross-lane row-sum reduce for l (16-lane groups)
#pragma unroll
  for (int off = 1; off < 16; off <<= 1)
#pragma unroll
    for (int c = 0; c < 4; ++c) l_run[c] += __shfl_xor(l_run[c], off);

  f32x4 inv;
#pragma unroll
  for (int c = 0; c < 4; ++c) inv[c] = 1.0f / l_run[c];
  const int b = bh >> 4, h = bh & 15;
#pragma unroll
  for (int dt = 0; dt < 4; ++dt) {
    const int col = h * 64 + dt * 16 + ln;
#pragma unroll
    for (int r = 0; r < 4; ++r) {
      const int srow = q0 + quad * 4 + r;
      Y[((size_t)(b * 2048 + srow)) * 1024 + col] = f2bf(o[dt][r] * inv[r]);
    }
  }
}

// ---------------------------------------------------------------------------
// fp32 in / fp32 out. d_out (16 MB) doubles as scratch.
// Merged path (ws >= 24 MB):
//   1. transpose WtA -> dout[0,6)
//   2. gemm<1,1> b=0 -> Q ws[0,8)+0  K ws[8,16)+0  V ws[16,24)+0 (heads 0-15)
//   3. gemm<1,1> b=1 -> same slots + 4 MB (heads 16-31)
//   4. attn merged (2048 blocks, lg_nbh=5) -> Y = dout[6,14)
//   5. transpose WtP -> ws[0,2)
//   6. gemm<0,0>(Y0=dout+6M) -> Cst=ws[4,12); copy -> dout[0,8)
//   7. gemm<0,0>(Y1=dout+10M) -> Cst; copy -> dout[8,16)
// Fallback (ws < 24 MB): exact round-8 schedule (lg_nbh=4, two attn launches).
// ---------------------------------------------------------------------------
extern "C" void kernel_launch(void* const* d_in, const int* in_sizes, int n_in,
                              void* d_out, int out_size, void* d_ws,
                              size_t ws_size, hipStream_t stream) {
  (void)in_sizes; (void)n_in; (void)out_size;
  const float* x  = (const float*)d_in[0];  // [2,2048,1024]
  const float* Wa = (const float*)d_in[1];  // [1024,3072]
  const float* ba = (const float*)d_in[2];  // [3072]
  const float* Wp = (const float*)d_in[3];  // [1024,1024]
  const float* bp = (const float*)d_in[4];  // [1024]

  char* ws = (char*)d_ws;
  char* outc = (char*)d_out;
  const size_t MB = 1024u * 1024u;

  if (ws_size >= 24 * MB) {
    u16* Q   = (u16*)(ws);             // [32][2048][64] (8 MB)
    u16* Kc  = (u16*)(ws + 8 * MB);    // (8 MB)
    u16* Vt  = (u16*)(ws + 16 * MB);   // [32][64][2048] (8 MB)
    u16* WtP = (u16*)(ws);             // after attn (Q dead)
    float* Cst = (float*)(ws + 4 * MB);
    u16* WtA = (u16*)(outc);
    u16* Yb  = (u16*)(outc + 6 * MB);  // [2][2048][1024] bf16 (8 MB)
    const size_t hb = (size_t)16 * 2048 * 64;  // 16 head-buffers

    transpose_f2b<<<dim3(48, 16), dim3(64, 4), 0, stream>>>(Wa, WtA, 1024,
                                                            3072);
    gemm_bt<1, 1><<<dim3(24, 16), 256, 0, stream>>>(
        nullptr, x, WtA, ba, nullptr, Q, Kc, Vt, 3072, 1024);
    gemm_bt<1, 1><<<dim3(24, 16), 256, 0, stream>>>(
        nullptr, x + (size_t)2048 * 1024, WtA, ba, nullptr, Q + hb, Kc + hb,
        Vt + hb, 3072, 1024);
    attn_fwd<<<dim3(2048), 128, 0, stream>>>(Q, Kc, Vt, Yb, 5);
    transpose_f2b<<<dim3(16, 16), dim3(64, 4), 0, stream>>>(Wp, WtP, 1024,
                                                            1024);
    gemm_bt<0, 0><<<dim3(8, 16), 256, 0, stream>>>(
        Yb, nullptr, WtP, bp, Cst, nullptr, nullptr, nullptr, 1024, 1024);
    hipMemcpyAsync(outc, Cst, 8 * MB, hipMemcpyDeviceToDevice, stream);
    gemm_bt<0, 0><<<dim3(8, 16), 256, 0, stream>>>(
        Yb + (size_t)2048 * 1024, nullptr, WtP, bp, Cst, nullptr, nullptr,
        nullptr, 1024, 1024);
    hipMemcpyAsync(outc + 8 * MB, Cst, 8 * MB, hipMemcpyDeviceToDevice,
                   stream);
  } else {
    u16* Q   = (u16*)(ws);
    u16* Kc  = (u16*)(ws + 4 * MB);
    u16* Vt  = (u16*)(ws + 8 * MB);
    u16* WtP = (u16*)(ws);
    float* Cst = (float*)(ws + 4 * MB);
    u16* WtA = (u16*)(outc);
    u16* Y0  = (u16*)(outc + 6 * MB);
    u16* Y1  = (u16*)(outc + 10 * MB);

    transpose_f2b<<<dim3(48, 16), dim3(64, 4), 0, stream>>>(Wa, WtA, 1024,
                                                            3072);
    gemm_bt<1, 1><<<dim3(24, 16), 256, 0, stream>>>(
        nullptr, x, WtA, ba, nullptr, Q, Kc, Vt, 3072, 1024);
    attn_fwd<<<dim3(1024), 128, 0, stream>>>(Q, Kc, Vt, Y0, 4);
    gemm_bt<1, 1><<<dim3(24, 16), 256, 0, stream>>>(
        nullptr, x + (size_t)2048 * 1024, WtA, ba, nullptr, Q, Kc, Vt, 3072,
        1024);
    attn_fwd<<<dim3(1024), 128, 0, stream>>>(Q, Kc, Vt, Y1, 4);
    transpose_f2b<<<dim3(16, 16), dim3(64, 4), 0, stream>>>(Wp, WtP, 1024,
                                                            1024);
    gemm_bt<0, 0><<<dim3(8, 16), 256, 0, stream>>>(
        Y0, nullptr, WtP, bp, Cst, nullptr, nullptr, nullptr, 1024, 1024);
    hipMemcpyAsync(outc, Cst, 8 * MB, hipMemcpyDeviceToDevice, stream);
    gemm_bt<0, 0><<<dim3(8, 16), 256, 0, stream>>>(
        Y1, nullptr, WtP, bp, Cst, nullptr, nullptr, nullptr, 1024, 1024);
    hipMemcpyAsync(outc + 8 * MB, Cst, 8 * MB, hipMemcpyDeviceToDevice,
                   stream);
  }
}

// Round 10
// 328.123 us; speedup vs baseline: 1.2566x; 1.2566x over previous
//
#include <hip/hip_runtime.h>
#include <cstdint>
#include <cmath>

typedef unsigned short u16;
typedef __bf16 bf16x8 __attribute__((ext_vector_type(8)));
typedef float  f32x4  __attribute__((ext_vector_type(4)));
typedef unsigned short u16x8 __attribute__((ext_vector_type(8)));

__device__ __forceinline__ u16 f2bf(float f) {
  unsigned u = __float_as_uint(f);
  u += 0x7fffu + ((u >> 16) & 1u);
  return (u16)(u >> 16);
}

#define NEG_BIG (-1.0e30f)

// ---------------------------------------------------------------------------
// Transpose + cast fp32 -> bf16: in [R][C] fp32 -> out [C][R] bf16. [proven]
// ---------------------------------------------------------------------------
__global__ __launch_bounds__(256) void transpose_f2b(
    const float* __restrict__ in, u16* __restrict__ out, int R, int C) {
  __shared__ u16 t[64][65];
  const int c0 = blockIdx.x << 6, r0 = blockIdx.y << 6;
  const int x = threadIdx.x, y0 = threadIdx.y;
#pragma unroll
  for (int yy = 0; yy < 64; yy += 4)
    t[yy + y0][x] = f2bf(in[(size_t)(r0 + yy + y0) * C + c0 + x]);
  __syncthreads();
#pragma unroll
  for (int yy = 0; yy < 64; yy += 4)
    out[(size_t)(c0 + yy + y0) * R + r0 + x] = t[x][yy + y0];
}

// ---------------------------------------------------------------------------
// C[M,N] = A[M,K] @ Bt[N,K]^T + bias(fp32). Bt bf16, fp32 accum.
// Plain LDS staging. [byte-frozen from rounds 7-9]
// ---------------------------------------------------------------------------
template <int MODE, int ADAPT_A>
__global__ __launch_bounds__(256, 2) void gemm_bt(
    const u16* __restrict__ A16, const float* __restrict__ AF,
    const u16* __restrict__ Bt, const float* __restrict__ biasF,
    float* __restrict__ out, u16* __restrict__ qb, u16* __restrict__ kb,
    u16* __restrict__ vt, int N, int K) {
  __shared__ u16 As[4096];
  __shared__ u16 Bs[4096];
  const int tid = threadIdx.x;
  const int lane = tid & 63;
  const int wave = tid >> 6;
  const int ln = lane & 15, quad = lane >> 4;
  const int wm = (wave >> 1) << 6, wn = (wave & 1) << 6;
  const int m0 = blockIdx.y << 7, n0 = blockIdx.x << 7;
  const int srow = tid >> 2, scol = (tid & 3) << 3;

  f32x4 acc[4][4] = {};

  for (int k0 = 0; k0 < K; k0 += 32) {
#pragma unroll
    for (int half = 0; half < 2; ++half) {
      const int arow = m0 + half * 64 + srow;
      u16* dstA = &As[half * 2048 + srow * 32 + scol];
      if (!ADAPT_A) {
        *(u16x8*)dstA = *(const u16x8*)(A16 + (size_t)arow * K + k0 + scol);
      } else {
        const float* p = AF + (size_t)arow * K + k0 + scol;
        u16x8 hv;
#pragma unroll
        for (int j = 0; j < 8; ++j) hv[j] = f2bf(p[j]);
        *(u16x8*)dstA = hv;
      }
      const int brow = n0 + half * 64 + srow;
      *(u16x8*)&Bs[half * 2048 + srow * 32 + scol] =
          *(const u16x8*)(Bt + (size_t)brow * K + k0 + scol);
    }
    __syncthreads();
    bf16x8 af[4], bfr[4];
#pragma unroll
    for (int t = 0; t < 4; ++t) {
      af[t] = *(const bf16x8*)&As[(wm + t * 16 + ln) * 32 + quad * 8];
      bfr[t] = *(const bf16x8*)&Bs[(wn + t * 16 + ln) * 32 + quad * 8];
    }
#pragma unroll
    for (int mt = 0; mt < 4; ++mt)
#pragma unroll
      for (int nt = 0; nt < 4; ++nt)
        acc[mt][nt] = __builtin_amdgcn_mfma_f32_16x16x32_bf16(
            af[mt], bfr[nt], acc[mt][nt], 0, 0, 0);
    __syncthreads();
  }

#pragma unroll
  for (int mt = 0; mt < 4; ++mt) {
#pragma unroll
    for (int nt = 0; nt < 4; ++nt) {
      const int col = n0 + wn + nt * 16 + ln;
      const float bv = biasF[col];
      const int rbase = m0 + wm + mt * 16 + quad * 4;
      if (MODE == 0) {
#pragma unroll
        for (int r = 0; r < 4; ++r)
          out[(size_t)(rbase + r) * N + col] = acc[mt][nt][r] + bv;
      } else {
        const int c = col & 1023;
        const int which = col >> 10;
        const int h = c >> 6, d = c & 63;
        if (which == 0) {
#pragma unroll
          for (int r = 0; r < 4; ++r)
            qb[((size_t)h * 2048 + rbase + r) * 64 + d] =
                f2bf(acc[mt][nt][r] + bv);
        } else if (which == 1) {
#pragma unroll
          for (int r = 0; r < 4; ++r)
            kb[((size_t)h * 2048 + rbase + r) * 64 + d] =
                f2bf(acc[mt][nt][r] + bv);
        } else {
          ushort4 pk;
          pk.x = f2bf(acc[mt][nt][0] + bv);
          pk.y = f2bf(acc[mt][nt][1] + bv);
          pk.z = f2bf(acc[mt][nt][2] + bv);
          pk.w = f2bf(acc[mt][nt][3] + bv);
          *(ushort4*)&vt[((size_t)h * 64 + d) * 2048 + rbase] = pk;
        }
      }
    }
  }
}

// ---------------------------------------------------------------------------
// Causal flash attention v6 = round-8 proven body (no K prefetch, VGPR~60,
// zero spill) + merged multi-batch launch (lg_nbh=5 -> 4 waves/SIMD).
// 1 wave = 16 q-rows of one (b,h); 64-key chunks; masked tiles skipped.
// No-max softmax: p = exp2(cs*s); l accumulated per-lane, reduced once.
// P per-wave, stride 72; wave-local s_waitcnt lgkmcnt(0).
// Q,K: [nbh][2048][64]; V^T: [nbh][64][2048]; Y: [nbh/16][2048][1024] bf16.
// ---------------------------------------------------------------------------
__global__ __launch_bounds__(128, 2) void attn_fwd(const u16* __restrict__ Qb,
                                                   const u16* __restrict__ Kb,
                                                   const u16* __restrict__ Vt,
                                                   u16* __restrict__ Y,
                                                   int lg_nbh) {
  __shared__ u16 P[2][1152];  // [wave][16 rows * 72]
  const int wave = threadIdx.x >> 6, lane = threadIdx.x & 63;
  const int ln = lane & 15, quad = lane >> 4;
  const int qtu = blockIdx.x >> (lg_nbh - 1);            // 0..127
  const int bh = ((blockIdx.x & ((1 << (lg_nbh - 1)) - 1)) << 1) + wave;
  const int qt = (qtu < 64) ? (127 - qtu) : (qtu - 64);  // heavy tasks first
  const int q0 = qt << 4;         // 16-row q-tile
  const int nch = (qt >> 2) + 1;  // 64-key chunks
  const u16* Qp = Qb + (size_t)bh * (2048 * 64);
  const u16* Kp = Kb + (size_t)bh * (2048 * 64);
  const u16* Vp = Vt + (size_t)bh * (64 * 2048);
  u16* Pw = P[wave];

  bf16x8 qf[2];
#pragma unroll
  for (int kk = 0; kk < 2; ++kk)
    qf[kk] = *(const bf16x8*)&Qp[(q0 + ln) * 64 + kk * 32 + quad * 8];

  f32x4 o[4] = {};
  f32x4 l_run = {};

  const float cs = 0.18033688011112042f;  // log2(e) / sqrt(64)

  for (int kc = 0; kc < nch; ++kc) {
    const int k0 = kc << 6;
    const int last = (kc == nch - 1);
    const int ant = last ? ((qt & 3) + 1) : 4;  // active 16-key tiles
    const int aks = (ant + 1) >> 1;             // active 32-key PV slices

    bf16x8 kf[4][2], vf[4][2];
#pragma unroll
    for (int nt = 0; nt < 4; ++nt)
      if (nt < ant)
#pragma unroll
        for (int kk = 0; kk < 2; ++kk)
          kf[nt][kk] = *(const bf16x8*)&Kp[(k0 + nt * 16 + ln) * 64 + kk * 32 +
                                           quad * 8];
#pragma unroll
    for (int ks = 0; ks < 2; ++ks)
      if (ks < aks)
#pragma unroll
        for (int dt = 0; dt < 4; ++dt)
          vf[dt][ks] = *(const bf16x8*)&Vp[(dt * 16 + ln) * 2048 + k0 +
                                           ks * 32 + quad * 8];

    f32x4 t[4] = {};  // zero-init: inactive tiles contribute p=0
#pragma unroll
    for (int nt = 0; nt < 4; ++nt)
      if (nt < ant) {
        f32x4 s = {};
        s = __builtin_amdgcn_mfma_f32_16x16x32_bf16(qf[0], kf[nt][0], s, 0, 0,
                                                    0);
        s = __builtin_amdgcn_mfma_f32_16x16x32_bf16(qf[1], kf[nt][1], s, 0, 0,
                                                    0);
        t[nt] = s * cs;
#pragma unroll
        for (int r = 0; r < 4; ++r) {
          if (last && (k0 + nt * 16 + ln > q0 + quad * 4 + r))
            t[nt][r] = NEG_BIG;                         // exp2 -> 0
          t[nt][r] = __builtin_amdgcn_exp2f(t[nt][r]);  // p in (0, ~2^14)
        }
        l_run += t[nt];  // order-free row-sum partial
      }

    // P (C-layout) -> LDS row-major [16 q][64 k], stride 72.
#pragma unroll
    for (int nt = 0; nt < 4; ++nt)
      if (nt < aks * 2)
#pragma unroll
        for (int r = 0; r < 4; ++r)
          Pw[(quad * 4 + r) * 72 + nt * 16 + ln] = f2bf(t[nt][r]);
    asm volatile("s_waitcnt lgkmcnt(0)" ::: "memory");  // own P writes done
    bf16x8 pa[2];
#pragma unroll
    for (int ks = 0; ks < 2; ++ks)
      if (ks < aks)
        pa[ks] = *(const bf16x8*)&Pw[ln * 72 + ks * 32 + quad * 8];
#pragma unroll
    for (int dt = 0; dt < 4; ++dt)
#pragma unroll
      for (int ks = 0; ks < 2; ++ks)
        if (ks < aks)
          o[dt] = __builtin_amdgcn_mfma_f32_16x16x32_bf16(pa[ks], vf[dt][ks],
                                                          o[dt], 0, 0, 0);
  }

  // one cross-lane row-sum reduce for l (16-lane groups)
#pragma unroll
  for (int off = 1; off < 16; off <<= 1)
#pragma unroll
    for (int c = 0; c < 4; ++c) l_run[c] += __shfl_xor(l_run[c], off);

  f32x4 inv;
#pragma unroll
  for (int c = 0; c < 4; ++c) inv[c] = 1.0f / l_run[c];
  const int b = bh >> 4, h = bh & 15;
#pragma unroll
  for (int dt = 0; dt < 4; ++dt) {
    const int col = h * 64 + dt * 16 + ln;
#pragma unroll
    for (int r = 0; r < 4; ++r) {
      const int srow = q0 + quad * 4 + r;
      Y[((size_t)(b * 2048 + srow)) * 1024 + col] = f2bf(o[dt][r] * inv[r]);
    }
  }
}

// ---------------------------------------------------------------------------
// Merged path (ws >= 24 MB): QKV for both batches resident, ONE attn launch.
// Fallback: round-8 proven two-launch schedule.
// ---------------------------------------------------------------------------
extern "C" void kernel_launch(void* const* d_in, const int* in_sizes, int n_in,
                              void* d_out, int out_size, void* d_ws,
                              size_t ws_size, hipStream_t stream) {
  (void)in_sizes; (void)n_in; (void)out_size;
  const float* x  = (const float*)d_in[0];  // [2,2048,1024]
  const float* Wa = (const float*)d_in[1];  // [1024,3072]
  const float* ba = (const float*)d_in[2];  // [3072]
  const float* Wp = (const float*)d_in[3];  // [1024,1024]
  const float* bp = (const float*)d_in[4];  // [1024]

  char* ws = (char*)d_ws;
  char* outc = (char*)d_out;
  const size_t MB = 1024u * 1024u;

  if (ws_size >= 24 * MB) {
    u16* Q   = (u16*)(ws);             // [32][2048][64] (8 MB)
    u16* Kc  = (u16*)(ws + 8 * MB);    // (8 MB)
    u16* Vt  = (u16*)(ws + 16 * MB);   // [32][64][2048] (8 MB)
    u16* WtP = (u16*)(ws);             // after attn (Q dead)
    float* Cst = (float*)(ws + 4 * MB);
    u16* WtA = (u16*)(outc);
    u16* Yb  = (u16*)(outc + 6 * MB);  // [2][2048][1024] bf16 (8 MB)
    const size_t hb = (size_t)16 * 2048 * 64;  // 16 head-buffers

    transpose_f2b<<<dim3(48, 16), dim3(64, 4), 0, stream>>>(Wa, WtA, 1024,
                                                            3072);
    gemm_bt<1, 1><<<dim3(24, 16), 256, 0, stream>>>(
        nullptr, x, WtA, ba, nullptr, Q, Kc, Vt, 3072, 1024);
    gemm_bt<1, 1><<<dim3(24, 16), 256, 0, stream>>>(
        nullptr, x + (size_t)2048 * 1024, WtA, ba, nullptr, Q + hb, Kc + hb,
        Vt + hb, 3072, 1024);
    attn_fwd<<<dim3(2048), 128, 0, stream>>>(Q, Kc, Vt, Yb, 5);
    transpose_f2b<<<dim3(16, 16), dim3(64, 4), 0, stream>>>(Wp, WtP, 1024,
                                                            1024);
    gemm_bt<0, 0><<<dim3(8, 16), 256, 0, stream>>>(
        Yb, nullptr, WtP, bp, Cst, nullptr, nullptr, nullptr, 1024, 1024);
    hipMemcpyAsync(outc, Cst, 8 * MB, hipMemcpyDeviceToDevice, stream);
    gemm_bt<0, 0><<<dim3(8, 16), 256, 0, stream>>>(
        Yb + (size_t)2048 * 1024, nullptr, WtP, bp, Cst, nullptr, nullptr,
        nullptr, 1024, 1024);
    hipMemcpyAsync(outc + 8 * MB, Cst, 8 * MB, hipMemcpyDeviceToDevice,
                   stream);
  } else {
    u16* Q   = (u16*)(ws);
    u16* Kc  = (u16*)(ws + 4 * MB);
    u16* Vt  = (u16*)(ws + 8 * MB);
    u16* WtP = (u16*)(ws);
    float* Cst = (float*)(ws + 4 * MB);
    u16* WtA = (u16*)(outc);
    u16* Y0  = (u16*)(outc + 6 * MB);
    u16* Y1  = (u16*)(outc + 10 * MB);

    transpose_f2b<<<dim3(48, 16), dim3(64, 4), 0, stream>>>(Wa, WtA, 1024,
                                                            3072);
    gemm_bt<1, 1><<<dim3(24, 16), 256, 0, stream>>>(
        nullptr, x, WtA, ba, nullptr, Q, Kc, Vt, 3072, 1024);
    attn_fwd<<<dim3(1024), 128, 0, stream>>>(Q, Kc, Vt, Y0, 4);
    gemm_bt<1, 1><<<dim3(24, 16), 256, 0, stream>>>(
        nullptr, x + (size_t)2048 * 1024, WtA, ba, nullptr, Q, Kc, Vt, 3072,
        1024);
    attn_fwd<<<dim3(1024), 128, 0, stream>>>(Q, Kc, Vt, Y1, 4);
    transpose_f2b<<<dim3(16, 16), dim3(64, 4), 0, stream>>>(Wp, WtP, 1024,
                                                            1024);
    gemm_bt<0, 0><<<dim3(8, 16), 256, 0, stream>>>(
        Y0, nullptr, WtP, bp, Cst, nullptr, nullptr, nullptr, 1024, 1024);
    hipMemcpyAsync(outc, Cst, 8 * MB, hipMemcpyDeviceToDevice, stream);
    gemm_bt<0, 0><<<dim3(8, 16), 256, 0, stream>>>(
        Y1, nullptr, WtP, bp, Cst, nullptr, nullptr, nullptr, 1024, 1024);
    hipMemcpyAsync(outc + 8 * MB, Cst, 8 * MB, hipMemcpyDeviceToDevice,
                   stream);
  }
}